// Round 1
// 589.046 us; speedup vs baseline: 1.0623x; 1.0623x over previous
//
#include <hip/hip_runtime.h>

#define N_ROW 512
#define N_COL 512
#define N_INT 768
#define N_SEG (N_INT - 1)
#define WPB 4
#define IMG_ELEMS (N_ROW * N_COL)

// -----------------------------------------------------------------------------
// Pre-pass: re-lay the 512x512 image into 4x4-pixel micro-tiles (64 B each).
// Tiled flat index bit layout (all fields disjoint):
//   bits [1:0]   = ci & 3
//   bits [3:2]   = ri & 3
//   bits [10:4]  = ci >> 2   (128 tiles per row)
//   bits [17:11] = ri >> 2
// One 64 B cache line == one 4x4 pixel square -> a gather spanning ~67 px of
// ray touches ~21-25 distinct lines instead of ~40-45 (row-major), for ANY
// ray angle. Pure permutation of values: numerics unchanged.
// -----------------------------------------------------------------------------
__global__ __launch_bounds__(256)
void tile_image_kernel(const float* __restrict__ img, float* __restrict__ img_t)
{
    const int idx    = blockIdx.x * 256 + threadIdx.x;   // index in TILED layout
    const int within = idx & 15;
    const int tile   = idx >> 4;
    const int tc = tile & 127;
    const int tr = tile >> 7;
    const int ri = (tr << 2) | (within >> 2);
    const int ci = (tc << 2) | (within & 3);
    img_t[idx] = img[ri * N_COL + ci];                   // coalesced store
}

// One wave per ray. Lane l, chunk c handles segment j = c*64 + l (c = 0..11):
// simultaneous lanes are ~1.05 px apart along the ray, so each gather spans
// ~67 px. All 12 t-loads issued upfront (MLP), marked non-temporal: t_sorted
// (403 MB) is single-use streaming and must not evict the L2-resident image.
// Neighbor t[j+1] via shfl (LDS pipe). Bit-exact numpy-fp32 elementwise
// pipeline: contract OFF (FMA contraction flips round() near .5 boundaries),
// rintf = half-to-even = np.round.
template<bool TILED>
__global__ __launch_bounds__(WPB * 64)
void ct_fwd_kernel(const float* __restrict__ image,
                   const float* __restrict__ t_sorted,
                   const float* __restrict__ M,
                   const float* __restrict__ b,
                   const float* __restrict__ src,
                   const float* __restrict__ dst,
                   float* __restrict__ out,
                   int n_ray)
{
#pragma clang fp contract(off)
    const int wave = threadIdx.x >> 6;
    const int lane = threadIdx.x & 63;
    const int ray  = blockIdx.x * WPB + wave;
    if (ray >= n_ray) return;

    // 2x2 inverse (adjugate/det), fp32, contract off — exact for identity M.
    const float m00 = M[0], m01 = M[1], m10 = M[2], m11 = M[3];
    const float det  = m00 * m11 - m01 * m10;
    const float rdet = 1.0f / det;
    const float i00 =  m11 * rdet;
    const float i01 = -(m01 * rdet);
    const float i10 = -(m10 * rdet);
    const float i11 =  m00 * rdet;
    const float b0 = b[0], b1 = b[1];

    const float sx  = __builtin_nontemporal_load(&src[2 * ray]);
    const float sy  = __builtin_nontemporal_load(&src[2 * ray + 1]);
    const float ddx = __builtin_nontemporal_load(&dst[2 * ray])     - sx;
    const float ddy = __builtin_nontemporal_load(&dst[2 * ray + 1]) - sy;

    const float* __restrict__ tp = t_sorted + (size_t)ray * N_INT;

    // 12 independent coalesced dword loads, all in flight before first use.
    // Non-temporal: single-use stream, keep it out of the image's cache space.
    float tv[12];
#pragma unroll
    for (int c = 0; c < 12; ++c)
        tv[c] = __builtin_nontemporal_load(&tp[c * 64 + lane]);

    // t[j+1] for j = c*64+lane: lane+1 of chunk c, or lane 0 of chunk c+1.
    float tu[12];
#pragma unroll
    for (int c = 0; c < 12; ++c) {
        float u = __shfl_down(tv[c], 1, 64);
        if (c < 11) {
            const float brd = __shfl(tv[c + 1], 0, 64);
            if (lane == 63) u = brd;
        }
        tu[c] = u;
    }

    float acc = 0.0f;
#pragma unroll
    for (int c = 0; c < 12; ++c) {
        const float t0 = tv[c];
        const float t1 = tu[c];

        // pts = src + t*(dst-src): mul rounded, then add rounded (no FMA)
        const float px0 = t0 * ddx;
        const float py0 = t0 * ddy;
        const float px1 = t1 * ddx;
        const float py1 = t1 * ddy;
        const float x0 = sx + px0;
        const float y0 = sy + py0;
        const float x1 = sx + px1;
        const float y1 = sy + py1;

        const float ex = x1 - x0;
        const float ey = y1 - y0;
        const float ex2 = ex * ex;
        const float ey2 = ey * ey;
        const float seg = __fsqrt_rn(ex2 + ey2);

        const float sxm = x0 + x1;
        const float sym = y0 + y1;
        const float mx = 0.5f * sxm - b0;
        const float my = 0.5f * sym - b1;

        const float r0 = i00 * mx;
        const float r1 = i01 * my;
        const float c0 = i10 * mx;
        const float c1 = i11 * my;
        const float rowf = r0 + r1;
        const float colf = c0 + c1;

        const int ri = (int)rintf(rowf);   // half-to-even == np.round
        const int ci = (int)rintf(colf);

        // segment j = c*64 + lane; only j == 767 is out of range.
        const bool segv = !((c == 11) & (lane == 63));
        const bool valid = (ri >= 0) & (ri < N_ROW) &
                           (ci >= 0) & (ci < N_COL) & segv;

        int flat;
        if (TILED) {
            // 4x4-tile bit-shuffle; ri,ci in [0,511] when valid.
            flat = valid ? (((ri >> 2) << 11) | ((ci >> 2) << 4) |
                            ((ri & 3) << 2)  | (ci & 3))
                         : 0;
        } else {
            flat = valid ? (ri * N_COL + ci) : 0;
        }
        const float pv = image[flat];
        acc += valid ? pv * seg : 0.0f;
    }

    // wave64 reduction
#pragma unroll
    for (int off = 32; off > 0; off >>= 1)
        acc += __shfl_down(acc, off, 64);

    if (lane == 0) __builtin_nontemporal_store(acc, &out[ray]);
}

extern "C" void kernel_launch(void* const* d_in, const int* in_sizes, int n_in,
                              void* d_out, int out_size, void* d_ws, size_t ws_size,
                              hipStream_t stream)
{
    const float* image    = (const float*)d_in[0];
    const float* t_sorted = (const float*)d_in[1];
    const float* M        = (const float*)d_in[2];
    const float* b        = (const float*)d_in[3];
    const float* src      = (const float*)d_in[4];
    const float* dst      = (const float*)d_in[5];
    float* out = (float*)d_out;

    const int n_ray = in_sizes[4] / 2;  // src is (n_ray, 2)
    const int grid = (n_ray + WPB - 1) / WPB;

    if (ws_size >= (size_t)IMG_ELEMS * sizeof(float)) {
        float* img_t = (float*)d_ws;
        tile_image_kernel<<<IMG_ELEMS / 256, 256, 0, stream>>>(image, img_t);
        ct_fwd_kernel<true><<<grid, WPB * 64, 0, stream>>>(
            img_t, t_sorted, M, b, src, dst, out, n_ray);
    } else {
        ct_fwd_kernel<false><<<grid, WPB * 64, 0, stream>>>(
            image, t_sorted, M, b, src, dst, out, n_ray);
    }
}

// Round 2
// 580.878 us; speedup vs baseline: 1.0772x; 1.0141x over previous
//
#include <hip/hip_runtime.h>

#define N_ROW 512
#define N_COL 512
#define N_INT 768
#define N_SEG (N_INT - 1)
#define WPB 4
#define IMG_ELEMS (N_ROW * N_COL)

// -----------------------------------------------------------------------------
// Pre-pass: re-lay the 512x512 image into 4x4-pixel micro-tiles (64 B each).
// Tiled flat index bit layout (all fields disjoint):
//   bits [1:0]   = ci & 3
//   bits [3:2]   = ri & 3
//   bits [10:4]  = ci >> 2   (128 tiles per row)
//   bits [17:11] = ri >> 2
// One 64 B line == one 4x4 pixel square: a gather spanning ~60 px of ray
// touches ~19-25 distinct lines instead of ~40-45 (row-major), isotropically.
// Pure permutation of values: numerics unchanged. (R1: part of the -37 us.)
// -----------------------------------------------------------------------------
__global__ __launch_bounds__(256)
void tile_image_kernel(const float* __restrict__ img, float* __restrict__ img_t)
{
    const int idx    = blockIdx.x * 256 + threadIdx.x;   // index in TILED layout
    const int within = idx & 15;
    const int tile   = idx >> 4;
    const int tc = tile & 127;
    const int tr = tile >> 7;
    const int ri = (tr << 2) | (within >> 2);
    const int ci = (tc << 2) | (within & 3);
    img_t[idx] = img[ri * N_COL + ci];                   // coalesced store
}

// -----------------------------------------------------------------------------
// Main body, templated on:
//   TILED — image is in 4x4-microtile layout (workspace path)
//   FASTM — M == identity && b == 0 (wave-uniform runtime check): rowf/colf
//           collapse to 0.5*(x0+x1), 0.5*(y0+y1). Bit-exact vs the generic
//           path for these inputs: 1*mx + 0*my == mx up to the sign of zero,
//           which is erased by the int round. Cuts ~8 VALU ops/segment off a
//           VALU pipe that R1 analysis shows is co-dominant with the HBM
//           stream (~60 us vs ~65 us per CU).
//
// Elementwise pipeline is bit-exact numpy-fp32: contract OFF (FMA contraction
// flips round() near .5 boundaries), rintf = half-to-even = np.round.
//
// Three-phase structure: (1) compute seg[12] + flat[12] (valid folded into
// seg=0 so the accumulate needs no select; pv*0 = +-0 is accumulation-
// neutral), (2) issue all 12 scattered gathers back-to-back (guaranteed MLP),
// (3) accumulate.
// -----------------------------------------------------------------------------
template<bool TILED, bool FASTM>
__device__ __forceinline__ void ct_body(
    const float* __restrict__ image, const float* __restrict__ tp,
    float sx, float sy, float ddx, float ddy,
    float i00, float i01, float i10, float i11, float b0, float b1,
    int lane, float* __restrict__ out, int ray)
{
#pragma clang fp contract(off)
    // 12 independent coalesced dword loads, all in flight before first use.
    // Non-temporal: t_sorted is a 403 MB single-use stream; keep it from
    // evicting the L2-resident image.
    float tv[12];
#pragma unroll
    for (int c = 0; c < 12; ++c)
        tv[c] = __builtin_nontemporal_load(&tp[c * 64 + lane]);

    float segz[12];
    int   flat[12];

#pragma unroll
    for (int c = 0; c < 12; ++c) {
        const float t0 = tv[c];
        // t[j+1] for j = c*64+lane: lane+1 of chunk c, or lane 0 of chunk c+1.
        float t1 = __shfl_down(tv[c], 1, 64);
        if (c < 11) {
            const float brd = __shfl(tv[c + 1], 0, 64);
            if (lane == 63) t1 = brd;
        }

        // pts = src + t*(dst-src): mul rounded, then add rounded (no FMA)
        const float px0 = t0 * ddx;
        const float py0 = t0 * ddy;
        const float px1 = t1 * ddx;
        const float py1 = t1 * ddy;
        const float x0 = sx + px0;
        const float y0 = sy + py0;
        const float x1 = sx + px1;
        const float y1 = sy + py1;

        const float ex = x1 - x0;
        const float ey = y1 - y0;
        const float seg = __fsqrt_rn(ex * ex + ey * ey);

        const float sxm = x0 + x1;
        const float sym = y0 + y1;

        float rowf, colf;
        if (FASTM) {
            rowf = 0.5f * sxm;
            colf = 0.5f * sym;
        } else {
            const float mx = 0.5f * sxm - b0;
            const float my = 0.5f * sym - b1;
            rowf = i00 * mx + i01 * my;
            colf = i10 * mx + i11 * my;
        }

        const int ri = (int)rintf(rowf);   // half-to-even == np.round
        const int ci = (int)rintf(colf);

        // segment j = c*64 + lane; only j == 767 is out of range.
        const bool segv  = !((c == 11) & (lane == 63));
        const bool valid = ((unsigned)ri < N_ROW) & ((unsigned)ci < N_COL) & segv;

        int f;
        if (TILED) {
            // 4x4-tile bit-shuffle; ri,ci in [0,511] when valid.
            f = ((ri & ~3) << 9) | ((((ci & ~3) | (ri & 3))) << 2) | (ci & 3);
        } else {
            f = ri * N_COL + ci;
        }
        flat[c] = valid ? f : 0;
        segz[c] = valid ? seg : 0.0f;   // pv * 0 contributes +-0: harmless
    }

    // Phase 2: all 12 gathers issued before any use.
    float pv[12];
#pragma unroll
    for (int c = 0; c < 12; ++c)
        pv[c] = image[flat[c]];

    // Phase 3: accumulate, then wave64 reduce.
    float acc = 0.0f;
#pragma unroll
    for (int c = 0; c < 12; ++c)
        acc += pv[c] * segz[c];

#pragma unroll
    for (int off = 32; off > 0; off >>= 1)
        acc += __shfl_down(acc, off, 64);

    if (lane == 0) __builtin_nontemporal_store(acc, &out[ray]);
}

template<bool TILED>
__global__ __launch_bounds__(WPB * 64)
void ct_fwd_kernel(const float* __restrict__ image,
                   const float* __restrict__ t_sorted,
                   const float* __restrict__ M,
                   const float* __restrict__ b,
                   const float* __restrict__ src,
                   const float* __restrict__ dst,
                   float* __restrict__ out,
                   int n_ray)
{
#pragma clang fp contract(off)
    const int wave = threadIdx.x >> 6;
    const int lane = threadIdx.x & 63;
    const int ray  = blockIdx.x * WPB + wave;
    if (ray >= n_ray) return;

    // 2x2 inverse (adjugate/det), fp32, contract off — exact for identity M.
    const float m00 = M[0], m01 = M[1], m10 = M[2], m11 = M[3];
    const float det  = m00 * m11 - m01 * m10;
    const float rdet = 1.0f / det;
    const float i00 =  m11 * rdet;
    const float i01 = -(m01 * rdet);
    const float i10 = -(m10 * rdet);
    const float i11 =  m00 * rdet;
    const float b0 = b[0], b1 = b[1];

    const float sx  = __builtin_nontemporal_load(&src[2 * ray]);
    const float sy  = __builtin_nontemporal_load(&src[2 * ray + 1]);
    const float ddx = __builtin_nontemporal_load(&dst[2 * ray])     - sx;
    const float ddy = __builtin_nontemporal_load(&dst[2 * ray + 1]) - sy;

    const float* __restrict__ tp = t_sorted + (size_t)ray * N_INT;

    // Wave-uniform specialization check (scalar branch, no divergence).
    const bool fastm = (m00 == 1.0f) & (m01 == 0.0f) &
                       (m10 == 0.0f) & (m11 == 1.0f) &
                       (b0 == 0.0f)  & (b1 == 0.0f);

    if (fastm)
        ct_body<TILED, true >(image, tp, sx, sy, ddx, ddy,
                              i00, i01, i10, i11, b0, b1, lane, out, ray);
    else
        ct_body<TILED, false>(image, tp, sx, sy, ddx, ddy,
                              i00, i01, i10, i11, b0, b1, lane, out, ray);
}

extern "C" void kernel_launch(void* const* d_in, const int* in_sizes, int n_in,
                              void* d_out, int out_size, void* d_ws, size_t ws_size,
                              hipStream_t stream)
{
    const float* image    = (const float*)d_in[0];
    const float* t_sorted = (const float*)d_in[1];
    const float* M        = (const float*)d_in[2];
    const float* b        = (const float*)d_in[3];
    const float* src      = (const float*)d_in[4];
    const float* dst      = (const float*)d_in[5];
    float* out = (float*)d_out;

    const int n_ray = in_sizes[4] / 2;  // src is (n_ray, 2)
    const int grid = (n_ray + WPB - 1) / WPB;

    if (ws_size >= (size_t)IMG_ELEMS * sizeof(float)) {
        float* img_t = (float*)d_ws;
        tile_image_kernel<<<IMG_ELEMS / 256, 256, 0, stream>>>(image, img_t);
        ct_fwd_kernel<true><<<grid, WPB * 64, 0, stream>>>(
            img_t, t_sorted, M, b, src, dst, out, n_ray);
    } else {
        ct_fwd_kernel<false><<<grid, WPB * 64, 0, stream>>>(
            image, t_sorted, M, b, src, dst, out, n_ray);
    }
}